// Round 1
// baseline (1513.289 us; speedup 1.0000x reference)
//
#include <hip/hip_runtime.h>
#include <math.h>

// ClassicMHSA: x(2,256,64,64) fp32, qkv_w(768,256), qkv_b(768), heads=8, hd=32
// Stage 1: Y[b][o][n] = sum_c W[o][c]*X[b][c][n] + bias[o]   (o=768, n=4096)
// Stage 2: per (b,h): S = Q^T K / sqrt(32); P = softmax_j(S); out[c][i] = sum_j P[i][j] V[c][j]
// Output layout: d_out[b][h*32+c][n]  (== reshape(b,256,64,64))

#define B_   2
#define CIN  256
#define COUT 768
#define NH   8
#define HD   32
#define NTOK 4096

// ---------------- Stage 1: QKV projection (tiled fp32 GEMM) ----------------
// grid (NTOK/64, COUT/64, B), block 256. 64x64 tile, 4x4 per thread, BK=16.
__global__ __launch_bounds__(256) void qkv_gemm(
    const float* __restrict__ X, const float* __restrict__ W,
    const float* __restrict__ bias, float* __restrict__ Y) {
  __shared__ float As[16][64];  // [k][m] : W transposed tile
  __shared__ float Bs[16][64];  // [k][n] : X tile

  const int t  = threadIdx.x;
  const int n0 = blockIdx.x * 64;
  const int o0 = blockIdx.y * 64;
  const int b  = blockIdx.z;
  const int tm = t >> 4, tn = t & 15;

  const int lam = t >> 2, lak = (t & 3) * 4;   // A-load: m=lam, k=lak..+3
  const int lbk = t >> 4, lbn = (t & 15) * 4;  // B-load: k=lbk, n=lbn..+3

  const float* Xb = X + (size_t)b * CIN * NTOK;
  float acc[4][4] = {};

  for (int kt = 0; kt < CIN; kt += 16) {
    float4 wv = *(const float4*)&W[(size_t)(o0 + lam) * CIN + kt + lak];
    As[lak + 0][lam] = wv.x;
    As[lak + 1][lam] = wv.y;
    As[lak + 2][lam] = wv.z;
    As[lak + 3][lam] = wv.w;
    *(float4*)&Bs[lbk][lbn] =
        *(const float4*)&Xb[(size_t)(kt + lbk) * NTOK + n0 + lbn];
    __syncthreads();
#pragma unroll
    for (int k = 0; k < 16; ++k) {
      float4 a  = *(const float4*)&As[k][tm * 4];
      float4 bv = *(const float4*)&Bs[k][tn * 4];
      float av[4] = {a.x, a.y, a.z, a.w};
      float bb[4] = {bv.x, bv.y, bv.z, bv.w};
#pragma unroll
      for (int i = 0; i < 4; ++i)
#pragma unroll
        for (int j = 0; j < 4; ++j)
          acc[i][j] = fmaf(av[i], bb[j], acc[i][j]);
    }
    __syncthreads();
  }
#pragma unroll
  for (int i = 0; i < 4; ++i) {
    float bs = bias[o0 + tm * 4 + i];
    float4 o4 = make_float4(acc[i][0] + bs, acc[i][1] + bs,
                            acc[i][2] + bs, acc[i][3] + bs);
    *(float4*)&Y[((size_t)b * COUT + o0 + tm * 4 + i) * NTOK + n0 + tn * 4] = o4;
  }
}

// ---------------- Stage 2: flash-style attention (fp32) ----------------
// grid (NTOK/64, B*NH), block 256 (4 waves).
// S-phase mapping: thread (tm=t>>4, tn=t&15) owns S[i=tm*4+di][j=tn*4+dj]
//   -> row i reduced across 16 consecutive lanes (shfl_xor 8/4/2/1).
// PV-phase mapping: thread (pcc=t>>4, pti=t&15) owns out[c=pcc*2+cc][i=pti+16*ii]
//   -> Ps rows read at lane-stride 68 floats (bank step 4: ~2-way, free).
__global__ __launch_bounds__(256) void attn(
    const float* __restrict__ Y, float* __restrict__ out) {
  __shared__ float Qs[HD][64];
  __shared__ float Ks[HD][64];
  __shared__ float Vs[HD][68];   // pad 68: PV broadcast reads conflict-free
  __shared__ float Ps[64][68];   // pad 68: lane-stride 68 -> ~2-way
  __shared__ float ms[64], ls[64], sfs[64];

  const int t  = threadIdx.x;
  const int i0 = blockIdx.x * 64;
  const int bh = blockIdx.y;
  const int b = bh >> 3, h = bh & 7;

  const float* Qg = Y + ((size_t)b * COUT + 0 * CIN + h * HD) * NTOK;
  const float* Kg = Y + ((size_t)b * COUT + 1 * CIN + h * HD) * NTOK;
  const float* Vg = Y + ((size_t)b * COUT + 2 * CIN + h * HD) * NTOK;

  {  // load Q tile [32][64]
    int c = t >> 4, i4 = (t & 15) * 4;
    *(float4*)&Qs[c][i4]      = *(const float4*)&Qg[(size_t)c * NTOK + i0 + i4];
    *(float4*)&Qs[c + 16][i4] = *(const float4*)&Qg[(size_t)(c + 16) * NTOK + i0 + i4];
  }
  if (t < 64) { ms[t] = -1e30f; ls[t] = 0.0f; }

  const int tm = t >> 4, tn = t & 15;   // S mapping
  const int pcc = t >> 4, pti = t & 15; // PV mapping

  float acc[2][4] = {};
  const float scale = 0.17677669529663688f;  // 1/sqrt(32)

  for (int jt = 0; jt < NTOK / 64; ++jt) {
    const int j0 = jt * 64;
    __syncthreads();  // prev PV done before K/V/P overwrite
    {
      int c = t >> 4, j4 = (t & 15) * 4;
      *(float4*)&Ks[c][j4]      = *(const float4*)&Kg[(size_t)c * NTOK + j0 + j4];
      *(float4*)&Ks[c + 16][j4] = *(const float4*)&Kg[(size_t)(c + 16) * NTOK + j0 + j4];
      *(float4*)&Vs[c][j4]      = *(const float4*)&Vg[(size_t)c * NTOK + j0 + j4];
      *(float4*)&Vs[c + 16][j4] = *(const float4*)&Vg[(size_t)(c + 16) * NTOK + j0 + j4];
    }
    __syncthreads();

    // ---- S = scale * Q^T K (4x4 per thread) ----
    float s[4][4] = {};
#pragma unroll
    for (int c = 0; c < HD; ++c) {
      float4 q  = *(const float4*)&Qs[c][tm * 4];
      float4 kk = *(const float4*)&Ks[c][tn * 4];
      float qa[4] = {q.x, q.y, q.z, q.w};
      float kb[4] = {kk.x, kk.y, kk.z, kk.w};
#pragma unroll
      for (int di = 0; di < 4; ++di)
#pragma unroll
        for (int dj = 0; dj < 4; ++dj)
          s[di][dj] = fmaf(qa[di], kb[dj], s[di][dj]);
    }
#pragma unroll
    for (int di = 0; di < 4; ++di)
#pragma unroll
      for (int dj = 0; dj < 4; ++dj) s[di][dj] *= scale;

    // ---- online softmax per row ----
#pragma unroll
    for (int di = 0; di < 4; ++di) {
      const int i = tm * 4 + di;
      float rmax = fmaxf(fmaxf(s[di][0], s[di][1]), fmaxf(s[di][2], s[di][3]));
#pragma unroll
      for (int off = 8; off; off >>= 1) rmax = fmaxf(rmax, __shfl_xor(rmax, off, 64));
      const float m_old = ms[i];
      const float m_new = fmaxf(m_old, rmax);
      float p[4], rsum = 0.0f;
#pragma unroll
      for (int dj = 0; dj < 4; ++dj) {
        p[dj] = __expf(s[di][dj] - m_new);
        rsum += p[dj];
      }
      *(float4*)&Ps[i][tn * 4] = make_float4(p[0], p[1], p[2], p[3]);
#pragma unroll
      for (int off = 8; off; off >>= 1) rsum += __shfl_xor(rsum, off, 64);
      if (tn == 0) {
        const float sf = __expf(m_old - m_new);
        sfs[i] = sf;
        ls[i] = ls[i] * sf + rsum;
        ms[i] = m_new;
      }
    }
    __syncthreads();

    // ---- PV: acc[c][i] = acc*sf + sum_j P[i][j] V[c][j] ----
    float sfv[4];
#pragma unroll
    for (int ii = 0; ii < 4; ++ii) sfv[ii] = sfs[pti + 16 * ii];
#pragma unroll
    for (int cc = 0; cc < 2; ++cc)
#pragma unroll
      for (int ii = 0; ii < 4; ++ii) acc[cc][ii] *= sfv[ii];

#pragma unroll
    for (int j4 = 0; j4 < 64; j4 += 4) {
      float4 v0 = *(const float4*)&Vs[pcc * 2 + 0][j4];
      float4 v1 = *(const float4*)&Vs[pcc * 2 + 1][j4];
#pragma unroll
      for (int ii = 0; ii < 4; ++ii) {
        float4 p = *(const float4*)&Ps[pti + 16 * ii][j4];
        acc[0][ii] = fmaf(p.w, v0.w, fmaf(p.z, v0.z, fmaf(p.y, v0.y, fmaf(p.x, v0.x, acc[0][ii]))));
        acc[1][ii] = fmaf(p.w, v1.w, fmaf(p.z, v1.z, fmaf(p.y, v1.y, fmaf(p.x, v1.x, acc[1][ii]))));
      }
    }
  }

  // ---- epilogue: divide by l, store ----
#pragma unroll
  for (int cc = 0; cc < 2; ++cc) {
    const int ch = h * HD + pcc * 2 + cc;
    float* og = out + ((size_t)b * CIN + ch) * NTOK + i0;
#pragma unroll
    for (int ii = 0; ii < 4; ++ii) {
      const int i = pti + 16 * ii;
      og[i] = acc[cc][ii] / ls[i];
    }
  }
}

extern "C" void kernel_launch(void* const* d_in, const int* in_sizes, int n_in,
                              void* d_out, int out_size, void* d_ws, size_t ws_size,
                              hipStream_t stream) {
  const float* x    = (const float*)d_in[0];
  const float* w    = (const float*)d_in[1];
  const float* bias = (const float*)d_in[2];
  float* outp = (float*)d_out;
  float* Y = (float*)d_ws;  // 2*768*4096 fp32 = 25.2 MB

  dim3 g1(NTOK / 64, COUT / 64, B_);
  qkv_gemm<<<g1, 256, 0, stream>>>(x, w, bias, Y);

  dim3 g2(NTOK / 64, B_ * NH);
  attn<<<g2, 256, 0, stream>>>(Y, outp);
}

// Round 2
// 451.297 us; speedup vs baseline: 3.3532x; 3.3532x over previous
//
#include <hip/hip_runtime.h>
#include <math.h>

// ClassicMHSA via split-bf16 MFMA (hi/lo 3-pass ~= fp32 accuracy).
// x(2,256,64,64) f32, qkv_w(768,256), qkv_b(768), heads=8, hd=32, n=4096.
//
// Pipeline:
//  1) xt_split : X[b][c][n] f32 -> Xthi/Xtlo [b][n][c] bf16   (in d_out scratch)
//  2) qkv_proj : MFMA GEMM -> Qhi/Qlo,Khi/Klo [bh][n][32], Vthi/Vtlo [bh][32][n] (ws)
//  3) attn_mfma: flash attention, QK^T + PV both 3-pass MFMA, softmax in-register.
//
// Layout safety: every MFMA loads BOTH operands with the same assumed k-bijection
// (k = 8*(lane>>4) + slot), so unknown A/B fragment k-order cancels (sum over k is
// permutation-invariant). Only the verified C/D layout (row=(lane>>4)*4+reg,
// col=lane&15) is relied upon (softmax rows, P store, epilogues).

#define B_   2
#define CIN  256
#define COUT 768
#define NH   8
#define HD   32
#define NTOK 4096
#define BH   (B_*NH)

typedef __attribute__((ext_vector_type(8))) short bf16x8;
typedef __attribute__((ext_vector_type(4))) float f32x4;

static __device__ __forceinline__ unsigned short f2bf(float f) {  // RNE f32->bf16
  unsigned u = __float_as_uint(f);
  unsigned r = ((u >> 16) & 1u) + 0x7fffu;
  return (unsigned short)((u + r) >> 16);
}
static __device__ __forceinline__ float bf2f(unsigned short h) {
  return __uint_as_float(((unsigned)h) << 16);
}

// ---------------- 1) X transpose + split ----------------
// grid (NTOK/4, B), block 256. Reads X[b][c][n4..n4+3] f32 (lane=c),
// writes Xthi/Xtlo[b][n][c] (lane-contiguous in c -> coalesced 2B x 256).
__global__ __launch_bounds__(256) void xt_split(
    const float* __restrict__ X,
    unsigned short* __restrict__ Xthi, unsigned short* __restrict__ Xtlo) {
  const int c = threadIdx.x;
  const int n4 = blockIdx.x * 4;
  const int b = blockIdx.y;
  float4 v = *(const float4*)&X[((size_t)(b * CIN + c)) * NTOK + n4];
  float vv[4] = {v.x, v.y, v.z, v.w};
#pragma unroll
  for (int k = 0; k < 4; ++k) {
    unsigned short hi = f2bf(vv[k]);
    unsigned short lo = f2bf(vv[k] - bf2f(hi));
    size_t idx = ((size_t)b * NTOK + n4 + k) * CIN + c;
    Xthi[idx] = hi;
    Xtlo[idx] = lo;
  }
}

// ---------------- 2) QKV projection (MFMA, no LDS) ----------------
// grid (COUT/64, NTOK/64, B), block 256 (4 waves). Wave w owns o-strip 16w.
// A = W (fp32, split to hi/lo in regs), B = Xt (pre-split bf16). K-loop 8x32.
__global__ __launch_bounds__(256) void qkv_proj(
    const float* __restrict__ W, const float* __restrict__ bias,
    const unsigned short* __restrict__ Xthi, const unsigned short* __restrict__ Xtlo,
    unsigned short* __restrict__ Qhi, unsigned short* __restrict__ Qlo,
    unsigned short* __restrict__ Khi, unsigned short* __restrict__ Klo,
    unsigned short* __restrict__ Vthi, unsigned short* __restrict__ Vtlo) {
  const int t = threadIdx.x;
  const int w = t >> 6, lane = t & 63, m = lane & 15, hi4 = lane >> 4;
  const int o0 = blockIdx.x * 64, n0 = blockIdx.y * 64, b = blockIdx.z;

  const int orow = o0 + 16 * w + m;  // A-frag row (D rows = o0+16w+4*hi4+r)
  f32x4 zero = {0.f, 0.f, 0.f, 0.f};
  f32x4 acc[4] = {zero, zero, zero, zero};

  for (int cs = 0; cs < CIN; cs += 32) {
    const float* wp = &W[(size_t)orow * CIN + cs + 8 * hi4];
    float4 wa = *(const float4*)wp;
    float4 wb = *(const float4*)(wp + 4);
    float wf[8] = {wa.x, wa.y, wa.z, wa.w, wb.x, wb.y, wb.z, wb.w};
    bf16x8 awh, awl;
#pragma unroll
    for (int k = 0; k < 8; ++k) {
      unsigned short h = f2bf(wf[k]);
      awh[k] = (short)h;
      awl[k] = (short)f2bf(wf[k] - bf2f(h));
    }
#pragma unroll
    for (int jt = 0; jt < 4; ++jt) {
      size_t xi = ((size_t)b * NTOK + n0 + 16 * jt + m) * CIN + cs + 8 * hi4;
      bf16x8 bxh = *(const bf16x8*)&Xthi[xi];
      bf16x8 bxl = *(const bf16x8*)&Xtlo[xi];
      acc[jt] = __builtin_amdgcn_mfma_f32_16x16x32_bf16(awl, bxh, acc[jt], 0, 0, 0);
      acc[jt] = __builtin_amdgcn_mfma_f32_16x16x32_bf16(awh, bxl, acc[jt], 0, 0, 0);
      acc[jt] = __builtin_amdgcn_mfma_f32_16x16x32_bf16(awh, bxh, acc[jt], 0, 0, 0);
    }
  }

  // epilogue: D[o][n], o = o0+16w+4*hi4+r, n = n0+16jt+m (verified C/D layout)
  const int qkv = o0 >> 8;              // 0=Q 1=K 2=V
  const int ohd = (o0 & 255) + 16 * w;  // offset within the 256-wide qkv part
  const int h = ohd >> 5;
  const int cb = (ohd & 31) + 4 * hi4;  // head-channel base (+r)
  const int bh = b * NH + h;
  float bs[4];
#pragma unroll
  for (int r = 0; r < 4; ++r) bs[r] = bias[o0 + 16 * w + 4 * hi4 + r];

#pragma unroll
  for (int jt = 0; jt < 4; ++jt) {
    const int n = n0 + 16 * jt + m;
    unsigned short ph[4], pl[4];
#pragma unroll
    for (int r = 0; r < 4; ++r) {
      float y = acc[jt][r] + bs[r];
      ph[r] = f2bf(y);
      pl[r] = f2bf(y - bf2f(ph[r]));
    }
    if (qkv < 2) {  // Q/K: [bh][n][32]
      unsigned short* dh = (qkv == 0 ? Qhi : Khi);
      unsigned short* dl = (qkv == 0 ? Qlo : Klo);
      size_t idx = ((size_t)bh * NTOK + n) * HD + cb;
      *(ushort4*)&dh[idx] = make_ushort4(ph[0], ph[1], ph[2], ph[3]);
      *(ushort4*)&dl[idx] = make_ushort4(pl[0], pl[1], pl[2], pl[3]);
    } else {  // V: transposed [bh][32][n]
#pragma unroll
      for (int r = 0; r < 4; ++r) {
        size_t idx = ((size_t)bh * HD + cb + r) * NTOK + n;
        Vthi[idx] = ph[r];
        Vtlo[idx] = pl[r];
      }
    }
  }
}

// ---------------- 3) Flash attention (MFMA) ----------------
// grid (NTOK/64, BH), block 256 (4 waves). Wave w owns query strip i0+16w..+15.
// j-loop has NO barriers: P round-trip through LDS is wave-local.
__global__ __launch_bounds__(256) void attn_mfma(
    const unsigned short* __restrict__ Qhi, const unsigned short* __restrict__ Qlo,
    const unsigned short* __restrict__ Khi, const unsigned short* __restrict__ Klo,
    const unsigned short* __restrict__ Vthi, const unsigned short* __restrict__ Vtlo,
    float* __restrict__ out) {
  __shared__ unsigned short Phi_s[64][72];  // rows padded to 144B (16B-aligned, even banks)
  __shared__ unsigned short Plo_s[64][72];

  const int t = threadIdx.x;
  const int w = t >> 6, lane = t & 63, m = lane & 15, hi4 = lane >> 4;
  const int i0 = blockIdx.x * 64;
  const int bh = blockIdx.y;

  // Q A-frags (persist across j-loop)
  size_t qi = ((size_t)bh * NTOK + i0 + 16 * w + m) * HD + 8 * hi4;
  const bf16x8 qh = *(const bf16x8*)&Qhi[qi];
  const bf16x8 ql = *(const bf16x8*)&Qlo[qi];

  f32x4 zero = {0.f, 0.f, 0.f, 0.f};
  f32x4 oacc[2] = {zero, zero};  // ct=0,1 -> out channels 16ct+m, rows i=16w+4*hi4+r
  float mrun[4] = {-1e30f, -1e30f, -1e30f, -1e30f};
  float lrun[4] = {0.f, 0.f, 0.f, 0.f};
  const float scale = 0.17677669529663688f;  // 1/sqrt(32)

  const unsigned short* Kb_h = Khi + (size_t)bh * NTOK * HD;
  const unsigned short* Kb_l = Klo + (size_t)bh * NTOK * HD;
  const unsigned short* Vb_h = Vthi + (size_t)bh * HD * NTOK;
  const unsigned short* Vb_l = Vtlo + (size_t)bh * HD * NTOK;

  for (int j0 = 0; j0 < NTOK; j0 += 64) {
    // ---- S = scale * Q^T K : rows i=16w+4*hi4+r, cols j=j0+16jt+m ----
    f32x4 s[4];
#pragma unroll
    for (int jt = 0; jt < 4; ++jt) {
      size_t ki = (size_t)(j0 + 16 * jt + m) * HD + 8 * hi4;
      bf16x8 kh = *(const bf16x8*)&Kb_h[ki];
      bf16x8 kl = *(const bf16x8*)&Kb_l[ki];
      f32x4 a = zero;
      a = __builtin_amdgcn_mfma_f32_16x16x32_bf16(ql, kh, a, 0, 0, 0);
      a = __builtin_amdgcn_mfma_f32_16x16x32_bf16(qh, kl, a, 0, 0, 0);
      a = __builtin_amdgcn_mfma_f32_16x16x32_bf16(qh, kh, a, 0, 0, 0);
#pragma unroll
      for (int r = 0; r < 4; ++r) s[jt][r] = a[r] * scale;
    }

    // ---- online softmax per row r (reduce over jt in-lane + 16 lanes) ----
    float sf[4];
#pragma unroll
    for (int r = 0; r < 4; ++r) {
      float mx = fmaxf(fmaxf(s[0][r], s[1][r]), fmaxf(s[2][r], s[3][r]));
      mx = fmaxf(mx, __shfl_xor(mx, 1));
      mx = fmaxf(mx, __shfl_xor(mx, 2));
      mx = fmaxf(mx, __shfl_xor(mx, 4));
      mx = fmaxf(mx, __shfl_xor(mx, 8));
      float mnew = fmaxf(mrun[r], mx);
      sf[r] = __expf(mrun[r] - mnew);
      mrun[r] = mnew;
      const int il = 16 * w + 4 * hi4 + r;
      float rsum = 0.f;
#pragma unroll
      for (int jt = 0; jt < 4; ++jt) {
        float p = __expf(s[jt][r] - mnew);
        rsum += p;
        unsigned short phv = f2bf(p);
        Phi_s[il][16 * jt + m] = phv;
        Plo_s[il][16 * jt + m] = f2bf(p - bf2f(phv));
      }
      rsum += __shfl_xor(rsum, 1);
      rsum += __shfl_xor(rsum, 2);
      rsum += __shfl_xor(rsum, 4);
      rsum += __shfl_xor(rsum, 8);
      lrun[r] = lrun[r] * sf[r] + rsum;
    }
#pragma unroll
    for (int ct = 0; ct < 2; ++ct)
#pragma unroll
      for (int r = 0; r < 4; ++r) oacc[ct][r] *= sf[r];

    // ---- PV: A = P (wave-local rows), B = Vt (global). 2 K-halves of 32 ----
#pragma unroll
    for (int kh2 = 0; kh2 < 2; ++kh2) {
      const bf16x8 pah = *(const bf16x8*)&Phi_s[16 * w + m][32 * kh2 + 8 * hi4];
      const bf16x8 pal = *(const bf16x8*)&Plo_s[16 * w + m][32 * kh2 + 8 * hi4];
#pragma unroll
      for (int ct = 0; ct < 2; ++ct) {
        size_t vi = (size_t)(16 * ct + m) * NTOK + j0 + 32 * kh2 + 8 * hi4;
        bf16x8 vh = *(const bf16x8*)&Vb_h[vi];
        bf16x8 vl = *(const bf16x8*)&Vb_l[vi];
        oacc[ct] = __builtin_amdgcn_mfma_f32_16x16x32_bf16(pal, vh, oacc[ct], 0, 0, 0);
        oacc[ct] = __builtin_amdgcn_mfma_f32_16x16x32_bf16(pah, vl, oacc[ct], 0, 0, 0);
        oacc[ct] = __builtin_amdgcn_mfma_f32_16x16x32_bf16(pah, vh, oacc[ct], 0, 0, 0);
      }
    }
  }

  // ---- epilogue: /l, transpose via LDS (reuses Phi_s), coalesced store ----
  __syncthreads();
  float* obuf = (float*)&Phi_s[0][0];  // [32][68] f32 (8704B <= 9216B)
#pragma unroll
  for (int ct = 0; ct < 2; ++ct)
#pragma unroll
    for (int r = 0; r < 4; ++r)
      obuf[(16 * ct + m) * 68 + 16 * w + 4 * hi4 + r] = oacc[ct][r] / lrun[r];
  __syncthreads();
  {
    const int c = t >> 3, i8 = (t & 7) * 8;
    const int b = bh >> 3, h = bh & 7;
    float* og = out + ((size_t)b * CIN + h * HD + c) * NTOK + i0 + i8;
    float4 v0 = *(const float4*)&obuf[c * 68 + i8];
    float4 v1 = *(const float4*)&obuf[c * 68 + i8 + 4];
    *(float4*)&og[0] = v0;
    *(float4*)&og[4] = v1;
  }
}

extern "C" void kernel_launch(void* const* d_in, const int* in_sizes, int n_in,
                              void* d_out, int out_size, void* d_ws, size_t ws_size,
                              hipStream_t stream) {
  const float* x    = (const float*)d_in[0];
  const float* w    = (const float*)d_in[1];
  const float* bias = (const float*)d_in[2];
  float* outp = (float*)d_out;

  // Xt (split bf16) lives in d_out scratch: 2 * 2*4096*256 * 2B = 8,388,608 B = out bytes.
  unsigned short* Xthi = (unsigned short*)d_out;
  unsigned short* Xtlo = Xthi + (size_t)B_ * NTOK * CIN;

  // ws: 6 arrays x (16*4096*32) bf16 = 25,165,824 B (== round-1 usage, proven OK)
  unsigned short* ws = (unsigned short*)d_ws;
  const size_t SZ = (size_t)BH * NTOK * HD;
  unsigned short* Qhi_ = ws + 0 * SZ;
  unsigned short* Qlo_ = ws + 1 * SZ;
  unsigned short* Khi_ = ws + 2 * SZ;
  unsigned short* Klo_ = ws + 3 * SZ;
  unsigned short* Vthi_ = ws + 4 * SZ;
  unsigned short* Vtlo_ = ws + 5 * SZ;

  xt_split<<<dim3(NTOK / 4, B_), 256, 0, stream>>>(x, Xthi, Xtlo);
  qkv_proj<<<dim3(COUT / 64, NTOK / 64, B_), 256, 0, stream>>>(
      w, bias, Xthi, Xtlo, Qhi_, Qlo_, Khi_, Klo_, Vthi_, Vtlo_);
  attn_mfma<<<dim3(NTOK / 64, BH), 256, 0, stream>>>(
      Qhi_, Qlo_, Khi_, Klo_, Vthi_, Vtlo_, outp);
}

// Round 3
// 310.822 us; speedup vs baseline: 4.8687x; 1.4519x over previous
//
#include <hip/hip_runtime.h>
#include <math.h>

// ClassicMHSA via split-bf16 MFMA, LDS-free flash attention (swapped QK^T).
// x(2,256,64,64) f32, qkv_w(768,256), qkv_b(768), heads=8, hd=32, n=4096.
//
//  1) xt_split : X[b][c][n] f32 -> Xthi/Xtlo [b][n][c] bf16 (LDS-transposed, coalesced)
//  2) qkv_proj : MFMA GEMM -> Qhi/Qlo, Khi/Klo [bh][n][32], Vthi [bh][32][n]
//  3) attn_mfma: flash attention. S^T = mfma(K,Q) so each lane owns one query
//     column -> softmax is 15 in-reg ops + 2 shuffles; P redistributed to the
//     PV B-fragment with 16 shuffles + 8 selects (no LDS, no barriers).
//     QK^T: 3-pass split-bf16. PV: 1-pass bf16 (error ~1e-4, see round-3 notes).
//
// Layout safety: every MFMA loads BOTH operands with the same assumed
// k-bijection (slot s at lane-group g <-> k = 8g+s), so the unknown HW k-order
// cancels. C/D layout (row=4*(lane>>4)+reg, col=lane&15) is the m89-verified one
// and was re-verified by rounds 1-2 passing at absmax 9.8e-4.

#define B_   2
#define CIN  256
#define COUT 768
#define NH   8
#define HD   32
#define NTOK 4096
#define BH   (B_*NH)

typedef __attribute__((ext_vector_type(8))) short bf16x8;
typedef __attribute__((ext_vector_type(4))) float f32x4;

static __device__ __forceinline__ unsigned short f2bf(float f) {  // RNE
  unsigned u = __float_as_uint(f);
  unsigned r = ((u >> 16) & 1u) + 0x7fffu;
  return (unsigned short)((u + r) >> 16);
}
static __device__ __forceinline__ float bf2f(unsigned short h) {
  return __uint_as_float(((unsigned)h) << 16);
}
// pack two POSITIVE floats to bf16 pair (round-half-up; p in (0,1])
static __device__ __forceinline__ unsigned packbf(float lo, float hi) {
  unsigned a = (__float_as_uint(lo) + 0x8000u) >> 16;
  unsigned b = (__float_as_uint(hi) + 0x8000u) & 0xffff0000u;
  return a | b;
}

// ---------------- 1) X transpose + split (coalesced, LDS transpose) --------
// grid (NTOK/64, CIN/64, B), block 256. 64c x 64n tile.
__global__ __launch_bounds__(256) void xt_split(
    const float* __restrict__ X,
    unsigned short* __restrict__ Xthi, unsigned short* __restrict__ Xtlo) {
  __shared__ unsigned tile[64][72];  // hi | lo<<16
  const int t = threadIdx.x;
  const int n0 = blockIdx.x * 64, c0 = blockIdx.y * 64, b = blockIdx.z;
  {
    const int cl = t >> 2, nb = (t & 3) * 16;
    const float* src = &X[((size_t)(b * CIN + c0 + cl)) * NTOK + n0 + nb];
#pragma unroll
    for (int q = 0; q < 4; ++q) {
      float4 v = *(const float4*)&src[4 * q];
      float vv[4] = {v.x, v.y, v.z, v.w};
#pragma unroll
      for (int e = 0; e < 4; ++e) {
        unsigned short h = f2bf(vv[e]);
        unsigned short l = f2bf(vv[e] - bf2f(h));
        tile[cl][nb + 4 * q + e] = (unsigned)h | ((unsigned)l << 16);
      }
    }
  }
  __syncthreads();
  {
    const int nl = t >> 2, cb = (t & 3) * 16;
    unsigned wh[8], wl[8];
#pragma unroll
    for (int j = 0; j < 8; ++j) {
      unsigned a = tile[cb + 2 * j][nl];
      unsigned bb = tile[cb + 2 * j + 1][nl];
      wh[j] = (a & 0xffffu) | (bb << 16);
      wl[j] = (a >> 16) | (bb & 0xffff0000u);
    }
    size_t base = ((size_t)b * NTOK + n0 + nl) * CIN + c0 + cb;
    uint4 u0, u1;
    u0.x = wh[0]; u0.y = wh[1]; u0.z = wh[2]; u0.w = wh[3];
    u1.x = wh[4]; u1.y = wh[5]; u1.z = wh[6]; u1.w = wh[7];
    *(uint4*)&Xthi[base] = u0;
    *(uint4*)&Xthi[base + 8] = u1;
    u0.x = wl[0]; u0.y = wl[1]; u0.z = wl[2]; u0.w = wl[3];
    u1.x = wl[4]; u1.y = wl[5]; u1.z = wl[6]; u1.w = wl[7];
    *(uint4*)&Xtlo[base] = u0;
    *(uint4*)&Xtlo[base + 8] = u1;
  }
}

// ---------------- 2) QKV projection (MFMA, no LDS) ----------------
__global__ __launch_bounds__(256) void qkv_proj(
    const float* __restrict__ W, const float* __restrict__ bias,
    const unsigned short* __restrict__ Xthi, const unsigned short* __restrict__ Xtlo,
    unsigned short* __restrict__ Qhi, unsigned short* __restrict__ Qlo,
    unsigned short* __restrict__ Khi, unsigned short* __restrict__ Klo,
    unsigned short* __restrict__ Vthi) {
  const int t = threadIdx.x;
  const int w = t >> 6, lane = t & 63, m = lane & 15, hi4 = lane >> 4;
  const int o0 = blockIdx.x * 64, n0 = blockIdx.y * 64, b = blockIdx.z;

  const int orow = o0 + 16 * w + m;
  f32x4 zero = {0.f, 0.f, 0.f, 0.f};
  f32x4 acc[4] = {zero, zero, zero, zero};

  for (int cs = 0; cs < CIN; cs += 32) {
    const float* wp = &W[(size_t)orow * CIN + cs + 8 * hi4];
    float4 wa = *(const float4*)wp;
    float4 wb = *(const float4*)(wp + 4);
    float wf[8] = {wa.x, wa.y, wa.z, wa.w, wb.x, wb.y, wb.z, wb.w};
    bf16x8 awh, awl;
#pragma unroll
    for (int k = 0; k < 8; ++k) {
      unsigned short h = f2bf(wf[k]);
      awh[k] = (short)h;
      awl[k] = (short)f2bf(wf[k] - bf2f(h));
    }
#pragma unroll
    for (int jt = 0; jt < 4; ++jt) {
      size_t xi = ((size_t)b * NTOK + n0 + 16 * jt + m) * CIN + cs + 8 * hi4;
      bf16x8 bxh = *(const bf16x8*)&Xthi[xi];
      bf16x8 bxl = *(const bf16x8*)&Xtlo[xi];
      acc[jt] = __builtin_amdgcn_mfma_f32_16x16x32_bf16(awl, bxh, acc[jt], 0, 0, 0);
      acc[jt] = __builtin_amdgcn_mfma_f32_16x16x32_bf16(awh, bxl, acc[jt], 0, 0, 0);
      acc[jt] = __builtin_amdgcn_mfma_f32_16x16x32_bf16(awh, bxh, acc[jt], 0, 0, 0);
    }
  }

  const int qkv = o0 >> 8;
  const int ohd = (o0 & 255) + 16 * w;
  const int h = ohd >> 5;
  const int cb = (ohd & 31) + 4 * hi4;
  const int bh = b * NH + h;
  float bs[4];
#pragma unroll
  for (int r = 0; r < 4; ++r) bs[r] = bias[o0 + 16 * w + 4 * hi4 + r];

#pragma unroll
  for (int jt = 0; jt < 4; ++jt) {
    const int n = n0 + 16 * jt + m;
    unsigned short ph[4], pl[4];
#pragma unroll
    for (int r = 0; r < 4; ++r) {
      float y = acc[jt][r] + bs[r];
      ph[r] = f2bf(y);
      pl[r] = f2bf(y - bf2f(ph[r]));
    }
    if (qkv < 2) {  // Q/K: [bh][n][32] hi+lo
      unsigned short* dh = (qkv == 0 ? Qhi : Khi);
      unsigned short* dl = (qkv == 0 ? Qlo : Klo);
      size_t idx = ((size_t)bh * NTOK + n) * HD + cb;
      *(ushort4*)&dh[idx] = make_ushort4(ph[0], ph[1], ph[2], ph[3]);
      *(ushort4*)&dl[idx] = make_ushort4(pl[0], pl[1], pl[2], pl[3]);
    } else {  // V: [bh][32][n] hi only
#pragma unroll
      for (int r = 0; r < 4; ++r)
        Vthi[((size_t)bh * HD + cb + r) * NTOK + n] = ph[r];
    }
  }
}

// ---------------- 3) Flash attention (LDS-free, swapped QK^T) ----------------
// grid (NTOK/64, BH), block 256 (4 waves, independent). Wave w: queries
// i = i0+16w+0..15; lane 16g+m owns query i=16w+m, S^T rows j=4g+r per tile.
__global__ __launch_bounds__(256, 4) void attn_mfma(
    const unsigned short* __restrict__ Qhi, const unsigned short* __restrict__ Qlo,
    const unsigned short* __restrict__ Khi, const unsigned short* __restrict__ Klo,
    const unsigned short* __restrict__ Vthi, float* __restrict__ out) {
  const int t = threadIdx.x;
  const int w = t >> 6, lane = t & 63, m = lane & 15, g = lane >> 4;
  const int i0 = blockIdx.x * 64;
  const int bh = blockIdx.y;

  size_t qi = ((size_t)bh * NTOK + i0 + 16 * w + m) * HD + 8 * g;
  const bf16x8 qh = *(const bf16x8*)&Qhi[qi];
  const bf16x8 ql = *(const bf16x8*)&Qlo[qi];

  const unsigned short* Kb_h = Khi + (size_t)bh * NTOK * HD;
  const unsigned short* Kb_l = Klo + (size_t)bh * NTOK * HD;
  const unsigned short* Vb   = Vthi + (size_t)bh * HD * NTOK;

  f32x4 zero = {0.f, 0.f, 0.f, 0.f};
  f32x4 oacc[2] = {zero, zero};  // D[c=16ct+4g+r][i=m]
  float mrun = -1e30f, lrun = 0.f;
  const float scale = 0.17677669529663688f;  // 1/sqrt(32)

  const int srcA = (g & 1) * 32 + m;  // B-frag gather base lane
  const bool ghi = (g >= 2);

  for (int j0 = 0; j0 < NTOK; j0 += 64) {
    // K fragments (A-operand rows j) and V fragments (A rows c) — loads early
    bf16x8 kf_h[4], kf_l[4], vf[2][2];
#pragma unroll
    for (int jt = 0; jt < 4; ++jt) {
      size_t ki = (size_t)(j0 + 16 * jt + m) * HD + 8 * g;
      kf_h[jt] = *(const bf16x8*)&Kb_h[ki];
      kf_l[jt] = *(const bf16x8*)&Kb_l[ki];
    }
#pragma unroll
    for (int k2 = 0; k2 < 2; ++k2)
#pragma unroll
      for (int ct = 0; ct < 2; ++ct)
        vf[k2][ct] = *(const bf16x8*)&Vb[(size_t)(16 * ct + m) * NTOK + j0 + 32 * k2 + 8 * g];

    // ---- S^T tiles: rows j=4g+r, col i=m (3-pass split-bf16) ----
    f32x4 s[4];
#pragma unroll
    for (int jt = 0; jt < 4; ++jt) {
      f32x4 a = zero;
      a = __builtin_amdgcn_mfma_f32_16x16x32_bf16(kf_l[jt], qh, a, 0, 0, 0);
      a = __builtin_amdgcn_mfma_f32_16x16x32_bf16(kf_h[jt], ql, a, 0, 0, 0);
      a = __builtin_amdgcn_mfma_f32_16x16x32_bf16(kf_h[jt], qh, a, 0, 0, 0);
#pragma unroll
      for (int r = 0; r < 4; ++r) s[jt][r] = a[r] * scale;
    }

    // ---- online softmax for query i=m (in-reg + xor16/32) ----
    float mx = s[0][0];
#pragma unroll
    for (int jt = 0; jt < 4; ++jt)
#pragma unroll
      for (int r = 0; r < 4; ++r) mx = fmaxf(mx, s[jt][r]);
    mx = fmaxf(mx, __shfl_xor(mx, 16, 64));
    mx = fmaxf(mx, __shfl_xor(mx, 32, 64));
    const float mnew = fmaxf(mrun, mx);
    const float sf = __expf(mrun - mnew);
    mrun = mnew;

    float rsum = 0.f;
    unsigned pw[4][2];
#pragma unroll
    for (int jt = 0; jt < 4; ++jt) {
      float p0 = __expf(s[jt][0] - mnew);
      float p1 = __expf(s[jt][1] - mnew);
      float p2 = __expf(s[jt][2] - mnew);
      float p3 = __expf(s[jt][3] - mnew);
      rsum += (p0 + p1) + (p2 + p3);
      pw[jt][0] = packbf(p0, p1);
      pw[jt][1] = packbf(p2, p3);
    }
    rsum += __shfl_xor(rsum, 16, 64);
    rsum += __shfl_xor(rsum, 32, 64);
    lrun = lrun * sf + rsum;
#pragma unroll
    for (int ct = 0; ct < 2; ++ct)
#pragma unroll
      for (int r = 0; r < 4; ++r) oacc[ct][r] *= sf;

    // ---- PV: A=V(rows c), B=P (assembled in-register) ----
#pragma unroll
    for (int k2 = 0; k2 < 2; ++k2) {
      const int tA = 2 * k2, tB = 2 * k2 + 1;
      unsigned w0a = __shfl((int)pw[tA][0], srcA, 64);
      unsigned w1a = __shfl((int)pw[tA][1], srcA, 64);
      unsigned w2a = __shfl((int)pw[tA][0], srcA + 16, 64);
      unsigned w3a = __shfl((int)pw[tA][1], srcA + 16, 64);
      unsigned w0b = __shfl((int)pw[tB][0], srcA, 64);
      unsigned w1b = __shfl((int)pw[tB][1], srcA, 64);
      unsigned w2b = __shfl((int)pw[tB][0], srcA + 16, 64);
      unsigned w3b = __shfl((int)pw[tB][1], srcA + 16, 64);
      union { unsigned u[4]; bf16x8 v; } pf;
      pf.u[0] = ghi ? w0b : w0a;
      pf.u[1] = ghi ? w1b : w1a;
      pf.u[2] = ghi ? w2b : w2a;
      pf.u[3] = ghi ? w3b : w3a;
      oacc[0] = __builtin_amdgcn_mfma_f32_16x16x32_bf16(vf[k2][0], pf.v, oacc[0], 0, 0, 0);
      oacc[1] = __builtin_amdgcn_mfma_f32_16x16x32_bf16(vf[k2][1], pf.v, oacc[1], 0, 0, 0);
    }
  }

  // ---- epilogue: divide by l, direct coalesced-ish stores ----
  const float inv = 1.0f / lrun;
  const int b = bh >> 3, h = bh & 7;
#pragma unroll
  for (int ct = 0; ct < 2; ++ct)
#pragma unroll
    for (int r = 0; r < 4; ++r) {
      const int c = h * HD + 16 * ct + 4 * g + r;
      out[((size_t)b * CIN + c) * NTOK + i0 + 16 * w + m] = oacc[ct][r] * inv;
    }
}

extern "C" void kernel_launch(void* const* d_in, const int* in_sizes, int n_in,
                              void* d_out, int out_size, void* d_ws, size_t ws_size,
                              hipStream_t stream) {
  const float* x    = (const float*)d_in[0];
  const float* w    = (const float*)d_in[1];
  const float* bias = (const float*)d_in[2];
  float* outp = (float*)d_out;

  // Xt (split bf16) in d_out scratch: 2 * (2*4096*256) * 2B = 8,388,608 B = out bytes.
  unsigned short* Xthi = (unsigned short*)d_out;
  unsigned short* Xtlo = Xthi + (size_t)B_ * NTOK * CIN;

  // ws: 5 arrays x 4 MB = 20 MB (ws proven >= 25 MB in rounds 1-2)
  unsigned short* ws = (unsigned short*)d_ws;
  const size_t SZ = (size_t)BH * NTOK * HD;
  unsigned short* Qhi_ = ws + 0 * SZ;
  unsigned short* Qlo_ = ws + 1 * SZ;
  unsigned short* Khi_ = ws + 2 * SZ;
  unsigned short* Klo_ = ws + 3 * SZ;
  unsigned short* Vthi_ = ws + 4 * SZ;

  xt_split<<<dim3(NTOK / 64, CIN / 64, B_), 256, 0, stream>>>(x, Xthi, Xtlo);
  qkv_proj<<<dim3(COUT / 64, NTOK / 64, B_), 256, 0, stream>>>(
      w, bias, Xthi, Xtlo, Qhi_, Qlo_, Khi_, Klo_, Vthi_);
  attn_mfma<<<dim3(NTOK / 64, BH), 256, 0, stream>>>(
      Qhi_, Qlo_, Khi_, Klo_, Vthi_, outp);
}